// Round 2
// baseline (13534.032 us; speedup 1.0000x reference)
//
#include <hip/hip_runtime.h>
#include <math.h>

// ---------------- problem constants ----------------
#define NEDU  1024
#define LTOK  20
#define CW    330     // 300 word + 30 pos
#define HDIM  256
#define FEAT  930
#define MSLOT 1026    // N_EDUS + 2
#define NWG   64      // parse workgroups; WG w owns elements 4w..4w+3 (one per wave)

// ---------------- workspace layout (32-bit word offsets) ----------------
#define O_WCATT 0
#define SZ_WCATT (330*600)
#define O_F     (O_WCATT + SZ_WCATT)
#define SZ_F    (NEDU*FEAT)
// loss partials overlap WCATT+F (both dead once parse runs): 2048 rows x 512 floats
#define O_LOSSP 0
#define SZ_LOSSP (2048*512)
#define O_BUFH  (O_F + SZ_F)
#define SZ_BUF  (MSLOT*HDIM)
#define O_BUFC  (O_BUFH + SZ_BUF)
#define O_STKT  (O_BUFC + SZ_BUF)          // tagged stack [2 parity][MSLOT][HDIM] u32
#define O_THT   (O_STKT + 2*SZ_BUF)        // tagged tracker h [2 parity][HDIM] u32
#define O_PART  (O_THT + 2*HDIM)           // 64 doubles loss partials (128 words)
#define NZERO   ((2*MSLOT + 2) * HDIM)     // stkT(2 par) + thT(2 par), zeros w/ tag 0

#define COMPOSED 0x40000000

typedef unsigned long long u64;

#define AG __HIP_MEMORY_SCOPE_AGENT
__device__ __forceinline__ u64 aload64(const u64* p) {
  return __hip_atomic_load(p, __ATOMIC_RELAXED, AG);
}
__device__ __forceinline__ void astore(unsigned* p, unsigned v) {
  __hip_atomic_store(p, v, __ATOMIC_RELAXED, AG);
}
__device__ __forceinline__ unsigned tagbits(float v, unsigned ver) {
  return (__float_as_uint(v) & ~3u) | (ver & 3u);
}
__device__ __forceinline__ float sigm(float x) { return 1.f / (1.f + expf(-x)); }

// gather one tagged 256-vector: lane gets elements 4l..4l+3; retry till all tags match
__device__ __forceinline__ void gather1T(const unsigned* base, int lane, unsigned tag,
                                         float* x) {
  const u64* p = (const u64*)base + 2 * lane;
  for (int it = 0;; ++it) {
    const u64 a = aload64(p), b = aload64(p + 1);
    const bool ok = (((unsigned)a & 3u) == tag) & (((unsigned)(a >> 32) & 3u) == tag) &
                    (((unsigned)b & 3u) == tag) & (((unsigned)(b >> 32) & 3u) == tag);
    if (__ballot(ok) == ~0ull) {
      x[0] = __uint_as_float((unsigned)a); x[1] = __uint_as_float((unsigned)(a >> 32));
      x[2] = __uint_as_float((unsigned)b); x[3] = __uint_as_float((unsigned)(b >> 32));
      return;
    }
    if (it > 48) __builtin_amdgcn_s_sleep(1);
  }
}
// spin on pre-issued pair of 8B loads until all tags match, then extract
__device__ __forceinline__ void spin4(const u64* p, u64 a, u64 b, unsigned tag, float* x) {
  for (int it = 0;; ++it) {
    const bool ok = (((unsigned)a & 3u) == tag) & (((unsigned)(a >> 32) & 3u) == tag) &
                    (((unsigned)b & 3u) == tag) & (((unsigned)(b >> 32) & 3u) == tag);
    if (__ballot(ok) == ~0ull) break;
    if (it > 40) __builtin_amdgcn_s_sleep(1);
    a = aload64(p); b = aload64(p + 1);
  }
  x[0] = __uint_as_float((unsigned)a); x[1] = __uint_as_float((unsigned)(a >> 32));
  x[2] = __uint_as_float((unsigned)b); x[3] = __uint_as_float((unsigned)(b >> 32));
}

// ---------------- prep: weight transpose + zeroing ----------------
__global__ void prep_kernel(const float* __restrict__ Wu, const float* __restrict__ Wb,
                            const float* __restrict__ Wt, float* __restrict__ ws) {
  const int i0 = blockIdx.x * blockDim.x + threadIdx.x;
  const int st = gridDim.x * blockDim.x;
  for (int i = i0; i < SZ_WCATT; i += st) {
    const int k = i / 600, c = i - 600 * k;
    float v;
    if (c < 100)      v = Wu[c * 330 + k];
    else if (c < 300) { const int q = c - 100; v = Wb[(q % 100) * 660 + (q / 100) * 330 + k]; }
    else              { const int q = c - 300; v = Wt[(q % 100) * 990 + (q / 100) * 330 + k]; }
    ws[O_WCATT + i] = v;
  }
  unsigned* z = (unsigned*)ws + O_STKT;
  for (int i = i0; i < NZERO; i += st) z[i] = 0u;              // zeros with ver-0 tags
  for (int i = i0; i < 2 * HDIM; i += st) {                    // buf zero rows 1024,1025
    ws[O_BUFH + NEDU * HDIM + i] = 0.f;
    ws[O_BUFC + NEDU * HDIM + i] = 0.f;
  }
}

// ---------------- encode (unchanged) ----------------
__global__ __launch_bounds__(256) void encode_kernel(
    const int* __restrict__ edu_words, const int* __restrict__ edu_poses,
    const float* __restrict__ word_emb, const float* __restrict__ pos_emb,
    const float* __restrict__ bu, const float* __restrict__ bb,
    const float* __restrict__ bt, float* __restrict__ ws) {
  __shared__ __align__(16) float xlT[CW * LTOK];
  __shared__ float zl[300 * 21];
  __shared__ float convout[300];
  const int n = blockIdx.x, tid = threadIdx.x;
  const float* WcatT = ws + O_WCATT;

  for (int i = tid; i < LTOK * CW; i += 256) {
    const int l = i / CW, k = i - l * CW;
    float v;
    if (k < 300) v = word_emb[(size_t)edu_words[n * LTOK + l] * 300 + k];
    else         v = pos_emb[(size_t)edu_poses[n * LTOK + l] * 30 + (k - 300)];
    xlT[k * LTOK + l] = v;
  }
  __syncthreads();

  for (int f = tid; f < 300; f += 256) {
    float acc[LTOK];
#pragma unroll
    for (int l = 0; l < LTOK; ++l) acc[l] = 0.f;
    for (int k = 0; k < CW; ++k) {
      const float w = WcatT[k * 600 + f];
      const float4* xp = (const float4*)(xlT + k * LTOK);
      union { float4 v[5]; float s[20]; } xu;
      xu.v[0] = xp[0]; xu.v[1] = xp[1]; xu.v[2] = xp[2]; xu.v[3] = xp[3]; xu.v[4] = xp[4];
#pragma unroll
      for (int l = 0; l < LTOK; ++l) acc[l] += w * xu.s[l];
    }
#pragma unroll
    for (int l = 0; l < LTOK; ++l) zl[f * 21 + l] = acc[l];
  }
  __syncthreads();
  if (tid < 200) {
    float m;
    if (tid < 100) {
      const int f = tid; const float b = bu[f];
      m = zl[f * 21] + b;
      for (int l = 1; l < 20; ++l) m = fmaxf(m, zl[f * 21 + l] + b);
    } else {
      const int f = tid - 100; const float b = bb[f];
      const float* z0 = zl + (100 + f) * 21;
      const float* z1 = zl + (200 + f) * 21;
      m = z1[0] + b;
      for (int u = 1; u <= 19; ++u) m = fmaxf(m, z0[u - 1] + z1[u] + b);
      m = fmaxf(m, z0[19] + b);
    }
    convout[tid] = fmaxf(m, 0.f);
  }
  __syncthreads();

  for (int f = tid; f < 300; f += 256) {
    float acc[LTOK];
#pragma unroll
    for (int l = 0; l < LTOK; ++l) acc[l] = 0.f;
    for (int k = 0; k < CW; ++k) {
      const float w = WcatT[k * 600 + 300 + f];
      const float4* xp = (const float4*)(xlT + k * LTOK);
      union { float4 v[5]; float s[20]; } xu;
      xu.v[0] = xp[0]; xu.v[1] = xp[1]; xu.v[2] = xp[2]; xu.v[3] = xp[3]; xu.v[4] = xp[4];
#pragma unroll
      for (int l = 0; l < LTOK; ++l) acc[l] += w * xu.s[l];
    }
#pragma unroll
    for (int l = 0; l < LTOK; ++l) zl[f * 21 + l] = acc[l];
  }
  __syncthreads();
  if (tid < 100) {
    const int f = tid; const float b = bt[f];
    const float* z0 = zl + f * 21;
    const float* z1 = zl + (100 + f) * 21;
    const float* z2 = zl + (200 + f) * 21;
    float m = z2[0] + b;
    m = fmaxf(m, z1[0] + z2[1] + b);
    for (int u = 2; u <= 19; ++u) m = fmaxf(m, z0[u - 2] + z1[u - 1] + z2[u] + b);
    m = fmaxf(m, z0[18] + z1[19] + b);
    m = fmaxf(m, z0[19] + b);
    convout[200 + f] = fmaxf(m, 0.f);
  }
  __syncthreads();

  float* Fr = ws + O_F + (size_t)n * FEAT;
  for (int j = tid; j < FEAT; j += 256) {
    float v;
    if (j < 300)      v = xlT[j * LTOK + 0];
    else if (j < 600) v = xlT[(j - 300) * LTOK + 19];
    else if (j < 630) v = xlT[(j - 300) * LTOK + 0];
    else              v = convout[j - 630];
    Fr[j] = v;
  }
}

// ---------------- proj (unchanged) ----------------
__global__ __launch_bounds__(256) void proj_kernel(const float* __restrict__ Wp,
                                                   const float* __restrict__ bp,
                                                   float* __restrict__ ws) {
  __shared__ float As[64][17];
  __shared__ float Bs[64][17];
  const float* F = ws + O_F;
  float* bufh = ws + O_BUFH;
  float* bufc = ws + O_BUFC;
  const int tid = threadIdx.x;
  const int m0 = blockIdx.x * 64, n0 = blockIdx.y * 64;
  const int mm0 = (tid & 15) * 4, nn0 = (tid >> 4) * 4;
  float acc[4][4] = {{0.f}};
  for (int k0 = 0; k0 < FEAT; k0 += 16) {
    for (int i = tid; i < 64 * 16; i += 256) {
      const int mm = i >> 4, kk = i & 15;
      const int gk = k0 + kk;
      As[mm][kk] = (gk < FEAT) ? F[(size_t)(m0 + mm) * FEAT + gk] : 0.f;
      Bs[mm][kk] = (gk < FEAT) ? Wp[(size_t)(n0 + mm) * FEAT + gk] : 0.f;
    }
    __syncthreads();
#pragma unroll
    for (int kk = 0; kk < 16; ++kk) {
      float av[4], bv[4];
#pragma unroll
      for (int i = 0; i < 4; ++i) av[i] = As[mm0 + i][kk];
#pragma unroll
      for (int jj = 0; jj < 4; ++jj) bv[jj] = Bs[nn0 + jj][kk];
#pragma unroll
      for (int i = 0; i < 4; ++i)
#pragma unroll
        for (int jj = 0; jj < 4; ++jj) acc[i][jj] += av[i] * bv[jj];
    }
    __syncthreads();
  }
#pragma unroll
  for (int i = 0; i < 4; ++i) {
    const int m = m0 + mm0 + i;
#pragma unroll
    for (int jj = 0; jj < 4; ++jj) {
      const int nn = n0 + nn0 + jj;
      const float v = acc[i][jj] + bp[nn];
      if (nn < 256) bufh[(size_t)m * 256 + nn] = v;
      else          bufc[(size_t)m * 256 + (nn - 256)] = v;
    }
  }
}

// ---------------- parse: 64 WGs x 4 waves; wave owns one element; no barriers ----------
// Wave q of WG w owns h-element j=4w+q: computes all 4 tracker gate rows and all 5
// compose gate rows for j (butterfly reduce, redundant nonlinearity in all lanes).
// Publication stays WG-local-line (4 consecutive 4B stores from one CU). Slot-source
// tracking (per-wave LDS tables, waves run identical control flow): pushed slots read
// straight from bufh/bufc (no coherent store on push!), most-recent composed vector
// register-cached, placeholders = zero rows. Only true broadcasts remain tagged:
// th every step + rh per REDUCE, both pre-issued to overlap static FMA work.
__global__ __launch_bounds__(256, 1) void parse_kernel(
    const int* __restrict__ transes, int nT,
    const float* __restrict__ Wih, const float* __restrict__ Whh,
    const float* __restrict__ bih, const float* __restrict__ bhh,
    const float* __restrict__ Wc, const float* __restrict__ bc,
    const float* __restrict__ Wsc, float* __restrict__ ws) {
  const int tid = threadIdx.x;
  const int lane = tid & 63;
  const int q = tid >> 6;                 // wave id = element sub-index
  const int j = blockIdx.x * 4 + q;       // owned h-element

  const float* bufh = ws + O_BUFH;
  const float* bufc = ws + O_BUFC;
  unsigned* stkT = (unsigned*)ws + O_STKT;
  unsigned* thT  = (unsigned*)ws + O_THT;
  float* lossp   = ws + O_LOSSP;

  __shared__ int   trs[2048];
  __shared__ int   ssrc[4][MSLOT];   // per-wave: buf row (<COMPOSED) or COMPOSED|ver
  __shared__ int   vcmp[4][MSLOT];   // per-wave: composition count per slot
  __shared__ float scsl[4][MSLOT];   // per-wave: rc of composed slots (own element)

  for (int i = tid; i < 2048; i += 256) trs[i] = (i < nT) ? transes[i] : 0;
  for (int i = lane; i < MSLOT; i += 64) {
    ssrc[q][i] = 1024;               // zero row of bufh/bufc
    vcmp[q][i] = 0;
    scsl[q][i] = 0.f;
  }
  __syncthreads();                   // one-time init sync only

  // ---- weight slices for element j: lane covers input cols 4*lane..4*lane+3 ----
  float wt[4][16]; float bt4[4];
#pragma unroll
  for (int g = 0; g < 4; ++g) {
    const int rg = g * 256 + j;
#pragma unroll
    for (int blk = 0; blk < 3; ++blk) {
      const float4 w = *(const float4*)(Wih + (size_t)rg * 768 + blk * 256 + 4 * lane);
      wt[g][4 * blk + 0] = w.x; wt[g][4 * blk + 1] = w.y;
      wt[g][4 * blk + 2] = w.z; wt[g][4 * blk + 3] = w.w;
    }
    const float4 wh = *(const float4*)(Whh + (size_t)rg * 256 + 4 * lane);
    wt[g][12] = wh.x; wt[g][13] = wh.y; wt[g][14] = wh.z; wt[g][15] = wh.w;
    bt4[g] = bih[rg] + bhh[rg];
  }
  float wcm[5][12]; float bc5[5];
#pragma unroll
  for (int g = 0; g < 5; ++g) {
    const int rg = g * 256 + j;
#pragma unroll
    for (int blk = 0; blk < 3; ++blk) {
      const float4 w = *(const float4*)(Wc + (size_t)rg * 768 + blk * 256 + 4 * lane);
      wcm[g][4 * blk + 0] = w.x; wcm[g][4 * blk + 1] = w.y;
      wcm[g][4 * blk + 2] = w.z; wcm[g][4 * blk + 3] = w.w;
    }
    bc5[g] = bc[rg];
  }
  const float ws0 = Wsc[j], ws1 = Wsc[256 + j];

  float tc = 0.f;                 // tracker cell for element j, replicated in lanes
  unsigned V = 0;
  int sptr = 2, bptr = 0;
  // register cache of most-recent composed full vector
  int ccSlot = -1, ccVer = -1;
  float cc0 = 0.f, cc1 = 0.f, cc2 = 0.f, cc3 = 0.f;

  auto bfly4 = [&](float& a0, float& a1, float& a2, float& a3) {
#pragma unroll
    for (int off = 32; off; off >>= 1) {
      a0 += __shfl_xor(a0, off, 64); a1 += __shfl_xor(a1, off, 64);
      a2 += __shfl_xor(a2, off, 64); a3 += __shfl_xor(a3, off, 64);
    }
  };
  auto bfly5 = [&](float& a0, float& a1, float& a2, float& a3, float& a4) {
#pragma unroll
    for (int off = 32; off; off >>= 1) {
      a0 += __shfl_xor(a0, off, 64); a1 += __shfl_xor(a1, off, 64);
      a2 += __shfl_xor(a2, off, 64); a3 += __shfl_xor(a3, off, 64);
      a4 += __shfl_xor(a4, off, 64);
    }
  };

  // resolve stack-slot h-vector (lane's 4 elements) without tagged traffic when possible
  auto resolveH = [&](int slot, float* x) {
    const int e = ssrc[q][slot];
    if (e < COMPOSED) {
      const float4 f = *(const float4*)(bufh + (size_t)e * HDIM + 4 * lane);
      x[0] = f.x; x[1] = f.y; x[2] = f.z; x[3] = f.w;
    } else {
      const int ver = e & 0xFFFF;
      if (slot == ccSlot && ver == ccVer) { x[0] = cc0; x[1] = cc1; x[2] = cc2; x[3] = cc3; }
      else gather1T(stkT + (size_t)(ver & 1) * SZ_BUF + (size_t)slot * HDIM, lane,
                    (unsigned)(ver & 3), x);
    }
  };
  // resolve stack-slot c (own element only)
  auto resolveC = [&](int slot) -> float {
    const int e = ssrc[q][slot];
    return (e < COMPOSED) ? bufc[(size_t)e * HDIM + j] : scsl[q][slot];
  };

  // finish tracker step: sums complete in all lanes; publish own th element + loss pair
  auto fin_track = [&](float s0, float s1, float s2, float s3) {
    const float gi = s0 + bt4[0], gf = s1 + bt4[1], gg = s2 + bt4[2], go = s3 + bt4[3];
    const float cn = sigm(gf) * tc + sigm(gi) * tanhf(gg);
    tc = cn;
    const float th = sigm(go) * tanhf(cn);
    if (lane == 0) {
      astore(thT + ((V + 1) & 1) * HDIM + j, tagbits(th, V + 1));
      float2 lp; lp.x = ws0 * th; lp.y = ws1 * th;
      *(float2*)(lossp + (size_t)V * 512 + 2 * j) = lp;
    }
  };

  // ---- initial track: p1 = p2 = 0, p3 = buf[0], th = 0 ----
  {
    const float4 f3 = *(const float4*)(bufh + 4 * lane);
    const float x3[4] = { f3.x, f3.y, f3.z, f3.w };
    float s0 = 0.f, s1 = 0.f, s2 = 0.f, s3 = 0.f;
#pragma unroll
    for (int c = 0; c < 4; ++c) {
      s0 += wt[0][8 + c] * x3[c]; s1 += wt[1][8 + c] * x3[c];
      s2 += wt[2][8 + c] * x3[c]; s3 += wt[3][8 + c] * x3[c];
    }
    bfly4(s0, s1, s2, s3);
    fin_track(s0, s1, s2, s3);
    V = 1;
  }

  for (int t = 0; t < nT; ++t) {
    const int tr = (t < 2048) ? trs[t] : transes[t];
    // pre-issue th(V) poll; travels while we resolve statics
    const u64* pt = (const u64*)(thT + (V & 1) * HDIM) + 2 * lane;
    u64 ta = aload64(pt), tb = aload64(pt + 1);
    if (tr) {
      // ==== compose: h1 = stack top (pushed -> bufh), h2 = below (cached/composed) ====
      const int sl1 = sptr - 1, sl2 = sptr - 2;
      float h1[4], h2[4];
      resolveH(sl1, h1);
      resolveH(sl2, h2);
      const float c1 = resolveC(sl1), c2 = resolveC(sl2);
      float a0 = 0.f, a1 = 0.f, a2 = 0.f, a3 = 0.f, a4 = 0.f;
#pragma unroll
      for (int c = 0; c < 4; ++c) {
        a0 += wcm[0][c] * h1[c] + wcm[0][4 + c] * h2[c];
        a1 += wcm[1][c] * h1[c] + wcm[1][4 + c] * h2[c];
        a2 += wcm[2][c] * h1[c] + wcm[2][4 + c] * h2[c];
        a3 += wcm[3][c] * h1[c] + wcm[3][4 + c] * h2[c];
        a4 += wcm[4][c] * h1[c] + wcm[4][4 + c] * h2[c];
      }
      float xth[4];
      spin4(pt, ta, tb, V & 3, xth);
#pragma unroll
      for (int c = 0; c < 4; ++c) {
        a0 += wcm[0][8 + c] * xth[c]; a1 += wcm[1][8 + c] * xth[c];
        a2 += wcm[2][8 + c] * xth[c]; a3 += wcm[3][8 + c] * xth[c];
        a4 += wcm[4][8 + c] * xth[c];
      }
      bfly5(a0, a1, a2, a3, a4);
      const float rc = tanhf(a0 + bc5[0]) * sigm(a1 + bc5[1])
                     + sigm(a2 + bc5[2]) * c1 + sigm(a3 + bc5[3]) * c2;
      const float rh = sigm(a4 + bc5[4]) * tanhf(rc);
      const int nv = vcmp[q][sl2] + 1;
      unsigned* sdst = stkT + (size_t)(nv & 1) * SZ_BUF + (size_t)sl2 * HDIM;
      if (lane == 0) {
        astore(sdst + j, tagbits(rh, (unsigned)nv));   // the rh broadcast
        vcmp[q][sl2] = nv;
        ssrc[q][sl2] = COMPOSED | nv;
        scsl[q][sl2] = rc;
      }
      // ==== trackR: p1 = rh (broadcast), p2 = slot sptr-3, p3 = buf[bptr], th reused ====
      const u64* pr = (const u64*)sdst + 2 * lane;
      u64 ra = aload64(pr), rb = aload64(pr + 1);      // pre-issue rh poll
      float p2[4];
      resolveH(sptr - 3, p2);                          // zero row / bufh in practice
      const float4 f3 = *(const float4*)(bufh + (size_t)bptr * HDIM + 4 * lane);
      const float x3[4] = { f3.x, f3.y, f3.z, f3.w };
      float s0 = 0.f, s1 = 0.f, s2 = 0.f, s3 = 0.f;
#pragma unroll
      for (int c = 0; c < 4; ++c) {
        s0 += wt[0][4 + c] * p2[c] + wt[0][8 + c] * x3[c] + wt[0][12 + c] * xth[c];
        s1 += wt[1][4 + c] * p2[c] + wt[1][8 + c] * x3[c] + wt[1][12 + c] * xth[c];
        s2 += wt[2][4 + c] * p2[c] + wt[2][8 + c] * x3[c] + wt[2][12 + c] * xth[c];
        s3 += wt[3][4 + c] * p2[c] + wt[3][8 + c] * x3[c] + wt[3][12 + c] * xth[c];
      }
      float rr[4];
      spin4(pr, ra, rb, (unsigned)(nv & 3), rr);
#pragma unroll
      for (int c = 0; c < 4; ++c) {
        s0 += wt[0][c] * rr[c]; s1 += wt[1][c] * rr[c];
        s2 += wt[2][c] * rr[c]; s3 += wt[3][c] * rr[c];
      }
      bfly4(s0, s1, s2, s3);
      fin_track(s0, s1, s2, s3);
      cc0 = rr[0]; cc1 = rr[1]; cc2 = rr[2]; cc3 = rr[3];
      ccSlot = sl2; ccVer = nv;
      V += 1; sptr -= 1;
    } else {
      // ==== trackS: push = pure bookkeeping (no coherent store!) ====
      const int slot = sptr;
      if (lane == 0) ssrc[q][slot] = bptr;
      if (slot == ccSlot) ccSlot = -1;      // pushed over the cached composed slot
      float p2[4];
      resolveH(sptr - 1, p2);
      const float4 f1 = *(const float4*)(bufh + (size_t)bptr * HDIM + 4 * lane);
      const float4 f3 = *(const float4*)(bufh + (size_t)(bptr + 1) * HDIM + 4 * lane);
      const float x1[4] = { f1.x, f1.y, f1.z, f1.w };
      const float x3[4] = { f3.x, f3.y, f3.z, f3.w };
      float s0 = 0.f, s1 = 0.f, s2 = 0.f, s3 = 0.f;
#pragma unroll
      for (int c = 0; c < 4; ++c) {
        s0 += wt[0][c] * x1[c] + wt[0][4 + c] * p2[c] + wt[0][8 + c] * x3[c];
        s1 += wt[1][c] * x1[c] + wt[1][4 + c] * p2[c] + wt[1][8 + c] * x3[c];
        s2 += wt[2][c] * x1[c] + wt[2][4 + c] * p2[c] + wt[2][8 + c] * x3[c];
        s3 += wt[3][c] * x1[c] + wt[3][4 + c] * p2[c] + wt[3][8 + c] * x3[c];
      }
      float xth[4];
      spin4(pt, ta, tb, V & 3, xth);
#pragma unroll
      for (int c = 0; c < 4; ++c) {
        s0 += wt[0][12 + c] * xth[c]; s1 += wt[1][12 + c] * xth[c];
        s2 += wt[2][12 + c] * xth[c]; s3 += wt[3][12 + c] * xth[c];
      }
      bfly4(s0, s1, s2, s3);
      fin_track(s0, s1, s2, s3);
      V += 1; sptr += 1; bptr += 1;
    }
  }
}

// ---------------- loss reduce: 64-WG partial pass + final pass ----------------
__global__ __launch_bounds__(256) void loss1_kernel(const int* __restrict__ transes, int nT,
                                                    const float* __restrict__ bsc,
                                                    const float* __restrict__ ws,
                                                    double* __restrict__ part) {
  const int tid = threadIdx.x;
  const float* lossp = ws + O_LOSSP;
  __shared__ float r0s[4], r1s[4];
  const float b0 = bsc[0], b1 = bsc[1];
  double acc = 0.0;
  const int t0 = blockIdx.x * 32;
  const int t1 = (t0 + 32 < nT) ? t0 + 32 : nT;
  for (int t = t0; t < t1; ++t) {
    const float2 p = *(const float2*)(lossp + (size_t)t * 512 + 2 * tid);
    float a0 = p.x, a1 = p.y;
#pragma unroll
    for (int off = 32; off; off >>= 1) {
      a0 += __shfl_down(a0, off, 64);
      a1 += __shfl_down(a1, off, 64);
    }
    if ((tid & 63) == 0) { r0s[tid >> 6] = a0; r1s[tid >> 6] = a1; }
    __syncthreads();
    if (tid == 0) {
      const float l0 = r0s[0] + r0s[1] + r0s[2] + r0s[3] + b0;
      const float l1 = r1s[0] + r1s[1] + r1s[2] + r1s[3] + b1;
      const float mx = fmaxf(l0, l1);
      acc += (double)(mx + logf(expf(l0 - mx) + expf(l1 - mx)) - (transes[t] ? l1 : l0));
    }
    __syncthreads();
  }
  if (tid == 0) part[blockIdx.x] = acc;
}

__global__ __launch_bounds__(64) void loss2_kernel(int nT, const double* __restrict__ part,
                                                   float* __restrict__ out) {
  double a = part[threadIdx.x];
#pragma unroll
  for (int off = 32; off; off >>= 1) a += __shfl_down(a, off, 64);
  if (threadIdx.x == 0) out[0] = (float)(a / (double)nT);
}

// ---------------- launch ----------------
extern "C" void kernel_launch(void* const* d_in, const int* in_sizes, int n_in,
                              void* d_out, int out_size, void* d_ws, size_t ws_size,
                              hipStream_t stream) {
  const int*   edu_words = (const int*)d_in[0];
  const int*   edu_poses = (const int*)d_in[1];
  const int*   transes   = (const int*)d_in[2];
  const float* word_emb  = (const float*)d_in[3];
  const float* pos_emb   = (const float*)d_in[4];
  const float* Wu  = (const float*)d_in[5];
  const float* bu  = (const float*)d_in[6];
  const float* Wb  = (const float*)d_in[7];
  const float* bb  = (const float*)d_in[8];
  const float* Wt  = (const float*)d_in[9];
  const float* bt  = (const float*)d_in[10];
  const float* Wp  = (const float*)d_in[11];
  const float* bp  = (const float*)d_in[12];
  const float* Wih = (const float*)d_in[13];
  const float* Whh = (const float*)d_in[14];
  const float* bih = (const float*)d_in[15];
  const float* bhh = (const float*)d_in[16];
  const float* Wc  = (const float*)d_in[17];
  const float* bc  = (const float*)d_in[18];
  const float* Wsc = (const float*)d_in[19];
  const float* bsc = (const float*)d_in[20];
  float* ws  = (float*)d_ws;
  float* out = (float*)d_out;
  int nT = in_sizes[2];

  hipLaunchKernelGGL(prep_kernel, dim3(256), dim3(256), 0, stream, Wu, Wb, Wt, ws);
  hipLaunchKernelGGL(encode_kernel, dim3(NEDU), dim3(256), 0, stream,
                     edu_words, edu_poses, word_emb, pos_emb, bu, bb, bt, ws);
  hipLaunchKernelGGL(proj_kernel, dim3(16, 8), dim3(256), 0, stream, Wp, bp, ws);

  void* args[] = { (void*)&transes, (void*)&nT, (void*)&Wih, (void*)&Whh, (void*)&bih,
                   (void*)&bhh, (void*)&Wc, (void*)&bc, (void*)&Wsc, (void*)&ws };
  hipLaunchCooperativeKernel((const void*)parse_kernel, dim3(NWG), dim3(256), args, 0, stream);

  double* part = (double*)(ws + O_PART);
  hipLaunchKernelGGL(loss1_kernel, dim3(64), dim3(256), 0, stream, transes, nT, bsc,
                     (const float*)ws, part);
  hipLaunchKernelGGL(loss2_kernel, dim3(1), dim3(64), 0, stream, nT,
                     (const double*)part, out);
}

// Round 4
// 7147.790 us; speedup vs baseline: 1.8935x; 1.8935x over previous
//
#include <hip/hip_runtime.h>
#include <math.h>

// ---------------- problem constants ----------------
#define NEDU  1024
#define LTOK  20
#define CW    330     // 300 word + 30 pos
#define HDIM  256
#define FEAT  930
#define MSLOT 1026    // N_EDUS + 2
#define NWG   64      // parse workgroups; WG w owns elements 4w..4w+3

// ---------------- workspace layout (32-bit word offsets) ----------------
#define O_WCATT 0
#define SZ_WCATT (330*600)
#define O_F     (O_WCATT + SZ_WCATT)
#define SZ_F    (NEDU*FEAT)
// loss partials overlap WCATT+F (both dead once parse runs): 2048 rows x 128 floats
#define O_LOSSP 0
#define O_BUFH  (O_F + SZ_F)
#define SZ_BUF  (MSLOT*HDIM)
#define O_BUFC  (O_BUFH + SZ_BUF)
#define O_STKT  (O_BUFC + SZ_BUF)          // tagged stack [2 parity][MSLOT][HDIM] u32
#define O_THTP  (O_STKT + 2*SZ_BUF)        // padded tracker h [2 parity][64 wg][16] u32
#define O_RHTP  (O_THTP + 2*1024)          // padded compose rh [2 parity][64 wg][16] u32
#define O_PART  (O_RHTP + 2*1024)          // 64 doubles loss partials (128 words)
#define NZERO   (2*SZ_BUF + 4*1024)        // stkT + thP + rhP zeros w/ tag 0

#define COMPOSED 0x40000000

typedef unsigned long long u64;

#define AG __HIP_MEMORY_SCOPE_AGENT
__device__ __forceinline__ u64 aload64(const u64* p) {
  return __hip_atomic_load(p, __ATOMIC_RELAXED, AG);
}
__device__ __forceinline__ void astore(unsigned* p, unsigned v) {
  __hip_atomic_store(p, v, __ATOMIC_RELAXED, AG);
}
__device__ __forceinline__ unsigned tagbits(float v, unsigned ver) {
  return (__float_as_uint(v) & ~3u) | (ver & 3u);
}
__device__ __forceinline__ float sigm(float x) { return 1.f / (1.f + expf(-x)); }

// raw WG barrier: waits LDS ops only, NOT vmem stores (no vmcnt drain)
__device__ __forceinline__ void sync_lds() {
  asm volatile("s_waitcnt lgkmcnt(0)\n\ts_barrier" ::: "memory");
}

// gather one tagged compact 256-vector (stkT): lane gets elements 4l..4l+3
__device__ __forceinline__ void gather1T(const unsigned* base, int lane, unsigned tag,
                                         float* x) {
  const u64* p = (const u64*)base + 2 * lane;
  for (int it = 0;; ++it) {
    const u64 a = aload64(p), b = aload64(p + 1);
    const bool ok = (((unsigned)a & 3u) == tag) & (((unsigned)(a >> 32) & 3u) == tag) &
                    (((unsigned)b & 3u) == tag) & (((unsigned)(b >> 32) & 3u) == tag);
    if (__ballot(ok) == ~0ull) {
      x[0] = __uint_as_float((unsigned)a); x[1] = __uint_as_float((unsigned)(a >> 32));
      x[2] = __uint_as_float((unsigned)b); x[3] = __uint_as_float((unsigned)(b >> 32));
      return;
    }
    if (it > 48) __builtin_amdgcn_s_sleep(1);
  }
}
// spin on pre-issued pair of 8B loads until all tags match, then extract
__device__ __forceinline__ void spin4(const u64* p, u64 a, u64 b, unsigned tag, float* x) {
  for (int it = 0;; ++it) {
    const bool ok = (((unsigned)a & 3u) == tag) & (((unsigned)(a >> 32) & 3u) == tag) &
                    (((unsigned)b & 3u) == tag) & (((unsigned)(b >> 32) & 3u) == tag);
    if (__ballot(ok) == ~0ull) break;
    if (it > 40) __builtin_amdgcn_s_sleep(1);
    a = aload64(p); b = aload64(p + 1);
  }
  x[0] = __uint_as_float((unsigned)a); x[1] = __uint_as_float((unsigned)(a >> 32));
  x[2] = __uint_as_float((unsigned)b); x[3] = __uint_as_float((unsigned)(b >> 32));
}

// ---------------- prep: weight transpose + zeroing ----------------
__global__ void prep_kernel(const float* __restrict__ Wu, const float* __restrict__ Wb,
                            const float* __restrict__ Wt, float* __restrict__ ws) {
  const int i0 = blockIdx.x * blockDim.x + threadIdx.x;
  const int st = gridDim.x * blockDim.x;
  for (int i = i0; i < SZ_WCATT; i += st) {
    const int k = i / 600, c = i - 600 * k;
    float v;
    if (c < 100)      v = Wu[c * 330 + k];
    else if (c < 300) { const int q = c - 100; v = Wb[(q % 100) * 660 + (q / 100) * 330 + k]; }
    else              { const int q = c - 300; v = Wt[(q % 100) * 990 + (q / 100) * 330 + k]; }
    ws[O_WCATT + i] = v;
  }
  unsigned* z = (unsigned*)ws + O_STKT;
  for (int i = i0; i < NZERO; i += st) z[i] = 0u;              // zeros with ver-0 tags
  for (int i = i0; i < 2 * HDIM; i += st) {                    // buf zero rows 1024,1025
    ws[O_BUFH + NEDU * HDIM + i] = 0.f;
    ws[O_BUFC + NEDU * HDIM + i] = 0.f;
  }
}

// ---------------- encode (unchanged) ----------------
__global__ __launch_bounds__(256) void encode_kernel(
    const int* __restrict__ edu_words, const int* __restrict__ edu_poses,
    const float* __restrict__ word_emb, const float* __restrict__ pos_emb,
    const float* __restrict__ bu, const float* __restrict__ bb,
    const float* __restrict__ bt, float* __restrict__ ws) {
  __shared__ __align__(16) float xlT[CW * LTOK];
  __shared__ float zl[300 * 21];
  __shared__ float convout[300];
  const int n = blockIdx.x, tid = threadIdx.x;
  const float* WcatT = ws + O_WCATT;

  for (int i = tid; i < LTOK * CW; i += 256) {
    const int l = i / CW, k = i - l * CW;
    float v;
    if (k < 300) v = word_emb[(size_t)edu_words[n * LTOK + l] * 300 + k];
    else         v = pos_emb[(size_t)edu_poses[n * LTOK + l] * 30 + (k - 300)];
    xlT[k * LTOK + l] = v;
  }
  __syncthreads();

  for (int f = tid; f < 300; f += 256) {
    float acc[LTOK];
#pragma unroll
    for (int l = 0; l < LTOK; ++l) acc[l] = 0.f;
    for (int k = 0; k < CW; ++k) {
      const float w = WcatT[k * 600 + f];
      const float4* xp = (const float4*)(xlT + k * LTOK);
      union { float4 v[5]; float s[20]; } xu;
      xu.v[0] = xp[0]; xu.v[1] = xp[1]; xu.v[2] = xp[2]; xu.v[3] = xp[3]; xu.v[4] = xp[4];
#pragma unroll
      for (int l = 0; l < LTOK; ++l) acc[l] += w * xu.s[l];
    }
#pragma unroll
    for (int l = 0; l < LTOK; ++l) zl[f * 21 + l] = acc[l];
  }
  __syncthreads();
  if (tid < 200) {
    float m;
    if (tid < 100) {
      const int f = tid; const float b = bu[f];
      m = zl[f * 21] + b;
      for (int l = 1; l < 20; ++l) m = fmaxf(m, zl[f * 21 + l] + b);
    } else {
      const int f = tid - 100; const float b = bb[f];
      const float* z0 = zl + (100 + f) * 21;
      const float* z1 = zl + (200 + f) * 21;
      m = z1[0] + b;
      for (int u = 1; u <= 19; ++u) m = fmaxf(m, z0[u - 1] + z1[u] + b);
      m = fmaxf(m, z0[19] + b);
    }
    convout[tid] = fmaxf(m, 0.f);
  }
  __syncthreads();

  for (int f = tid; f < 300; f += 256) {
    float acc[LTOK];
#pragma unroll
    for (int l = 0; l < LTOK; ++l) acc[l] = 0.f;
    for (int k = 0; k < CW; ++k) {
      const float w = WcatT[k * 600 + 300 + f];
      const float4* xp = (const float4*)(xlT + k * LTOK);
      union { float4 v[5]; float s[20]; } xu;
      xu.v[0] = xp[0]; xu.v[1] = xp[1]; xu.v[2] = xp[2]; xu.v[3] = xp[3]; xu.v[4] = xp[4];
#pragma unroll
      for (int l = 0; l < LTOK; ++l) acc[l] += w * xu.s[l];
    }
#pragma unroll
    for (int l = 0; l < LTOK; ++l) zl[f * 21 + l] = acc[l];
  }
  __syncthreads();
  if (tid < 100) {
    const int f = tid; const float b = bt[f];
    const float* z0 = zl + f * 21;
    const float* z1 = zl + (100 + f) * 21;
    const float* z2 = zl + (200 + f) * 21;
    float m = z2[0] + b;
    m = fmaxf(m, z1[0] + z2[1] + b);
    for (int u = 2; u <= 19; ++u) m = fmaxf(m, z0[u - 2] + z1[u - 1] + z2[u] + b);
    m = fmaxf(m, z0[18] + z1[19] + b);
    m = fmaxf(m, z0[19] + b);
    convout[200 + f] = fmaxf(m, 0.f);
  }
  __syncthreads();

  float* Fr = ws + O_F + (size_t)n * FEAT;
  for (int j = tid; j < FEAT; j += 256) {
    float v;
    if (j < 300)      v = xlT[j * LTOK + 0];
    else if (j < 600) v = xlT[(j - 300) * LTOK + 19];
    else if (j < 630) v = xlT[(j - 300) * LTOK + 0];
    else              v = convout[j - 630];
    Fr[j] = v;
  }
}

// ---------------- proj (unchanged) ----------------
__global__ __launch_bounds__(256) void proj_kernel(const float* __restrict__ Wp,
                                                   const float* __restrict__ bp,
                                                   float* __restrict__ ws) {
  __shared__ float As[64][17];
  __shared__ float Bs[64][17];
  const float* F = ws + O_F;
  float* bufh = ws + O_BUFH;
  float* bufc = ws + O_BUFC;
  const int tid = threadIdx.x;
  const int m0 = blockIdx.x * 64, n0 = blockIdx.y * 64;
  const int mm0 = (tid & 15) * 4, nn0 = (tid >> 4) * 4;
  float acc[4][4] = {{0.f}};
  for (int k0 = 0; k0 < FEAT; k0 += 16) {
    for (int i = tid; i < 64 * 16; i += 256) {
      const int mm = i >> 4, kk = i & 15;
      const int gk = k0 + kk;
      As[mm][kk] = (gk < FEAT) ? F[(size_t)(m0 + mm) * FEAT + gk] : 0.f;
      Bs[mm][kk] = (gk < FEAT) ? Wp[(size_t)(n0 + mm) * FEAT + gk] : 0.f;
    }
    __syncthreads();
#pragma unroll
    for (int kk = 0; kk < 16; ++kk) {
      float av[4], bv[4];
#pragma unroll
      for (int i = 0; i < 4; ++i) av[i] = As[mm0 + i][kk];
#pragma unroll
      for (int jj = 0; jj < 4; ++jj) bv[jj] = Bs[nn0 + jj][kk];
#pragma unroll
      for (int i = 0; i < 4; ++i)
#pragma unroll
        for (int jj = 0; jj < 4; ++jj) acc[i][jj] += av[i] * bv[jj];
    }
    __syncthreads();
  }
#pragma unroll
  for (int i = 0; i < 4; ++i) {
    const int m = m0 + mm0 + i;
#pragma unroll
    for (int jj = 0; jj < 4; ++jj) {
      const int nn = n0 + nn0 + jj;
      const float v = acc[i][jj] + bp[nn];
      if (nn < 256) bufh[(size_t)m * 256 + nn] = v;
      else          bufc[(size_t)m * 256 + (nn - 256)] = v;
    }
  }
}

// ---------------- parse: R0 skeleton + padded 1-writer broadcast lines ----------------
// 64 WGs x 4 waves. Wave wv computes gate wv for the WG's 4 elements (gate-split),
// g_lds exchange + tid<4 finish + single coalesced 16B publication into the WG's OWN
// 64B cache line of the padded broadcast buffer (1 writer per line chip-wide).
// PADDED LAYOUT: [2 parity][64 wg][16 u32]; element j=4w+q at u32 w*16+q. Consumer
// lane l reads WG l's line: u64 index 8*l (+1) -> u32 16l..16l+3 = elements 4l..4l+3.
// Pushes are LDS bookkeeping only (ssrc); pushed slots read from bufh (plain loads);
// last-composed vector register-cached -> steady state has no stack gathers.
__global__ __launch_bounds__(256, 1) void parse_kernel(
    const int* __restrict__ transes, int nT,
    const float* __restrict__ Wih, const float* __restrict__ Whh,
    const float* __restrict__ bih, const float* __restrict__ bhh,
    const float* __restrict__ Wc, const float* __restrict__ bc,
    const float* __restrict__ Wsc, float* __restrict__ ws) {
  const int tid = threadIdx.x;
  const int lane = tid & 63;
  const int wv = tid >> 6;
  const int bx = blockIdx.x;
  const int j0 = bx * 4;

  const float* bufh = ws + O_BUFH;
  const float* bufc = ws + O_BUFC;
  unsigned* stkT = (unsigned*)ws + O_STKT;
  unsigned* thP  = (unsigned*)ws + O_THTP;   // [2][64][16]
  unsigned* rhP  = (unsigned*)ws + O_RHTP;   // [2][64][16]
  float* lossp   = ws + O_LOSSP;

  __shared__ int   trs[2048];
  __shared__ int   ssrc[MSLOT];      // buf row (<COMPOSED) or COMPOSED|ver
  __shared__ int   vcmp[MSLOT];      // composition count per slot
  __shared__ float sc_lds[MSLOT][4]; // stack c for WG's own 4 elements
  __shared__ float tc_lds[2][4];
  __shared__ float g_lds[20];
  __shared__ float part_lds[8];

  for (int i = tid; i < 2048; i += 256) trs[i] = (i < nT) ? transes[i] : 0;
  for (int i = tid; i < MSLOT; i += 256) { ssrc[i] = 1024; vcmp[i] = 0; }
  for (int i = tid; i < MSLOT * 4; i += 256) ((float*)sc_lds)[i] = 0.f;
  if (tid < 4) { tc_lds[0][tid] = 0.f; tc_lds[1][tid] = 0.f; }
  __syncthreads();

  // ---- weight slices (gate-split, element e = 4*lane + c of each input block) ----
  float wt[4][16]; float bt_[4];
#pragma unroll
  for (int q = 0; q < 4; ++q) {
    const int rg = wv * 256 + j0 + q;          // gate wv, element j0+q
#pragma unroll
    for (int blk = 0; blk < 3; ++blk) {
      const float4 w = *(const float4*)(Wih + (size_t)rg * 768 + blk * 256 + 4 * lane);
      wt[q][4 * blk + 0] = w.x; wt[q][4 * blk + 1] = w.y;
      wt[q][4 * blk + 2] = w.z; wt[q][4 * blk + 3] = w.w;
    }
    const float4 wh = *(const float4*)(Whh + (size_t)rg * 256 + 4 * lane);
    wt[q][12] = wh.x; wt[q][13] = wh.y; wt[q][14] = wh.z; wt[q][15] = wh.w;
    bt_[q] = bih[rg] + bhh[rg];
  }
  float wcm[5][12]; float bc_[5];
#pragma unroll
  for (int q = 0; q < 5; ++q) {
    const int row = 5 * wv + q, gate = row >> 2, jj = row & 3;
    const int rg = gate * 256 + j0 + jj;
#pragma unroll
    for (int blk = 0; blk < 3; ++blk) {
      const float4 w = *(const float4*)(Wc + (size_t)rg * 768 + blk * 256 + 4 * lane);
      wcm[q][4 * blk + 0] = w.x; wcm[q][4 * blk + 1] = w.y;
      wcm[q][4 * blk + 2] = w.z; wcm[q][4 * blk + 3] = w.w;
    }
    bc_[q] = bc[rg];
  }
  float ws0 = 0.f, ws1 = 0.f;
  if (tid < 4) { ws0 = Wsc[j0 + tid]; ws1 = Wsc[256 + j0 + tid]; }

  unsigned V = 0, vrh = 0;
  int sptr = 2, bptr = 0;
  // register cache of most-recent composed vector (per-lane 4 elements)
  int ccSlot = -1, ccVer = -1;
  float cc0 = 0.f, cc1 = 0.f, cc2 = 0.f, cc3 = 0.f;

  auto red4 = [&](float& a0, float& a1, float& a2, float& a3) {
#pragma unroll
    for (int off = 32; off; off >>= 1) {
      a0 += __shfl_down(a0, off, 64); a1 += __shfl_down(a1, off, 64);
      a2 += __shfl_down(a2, off, 64); a3 += __shfl_down(a3, off, 64);
    }
  };
  auto red5 = [&](float& a0, float& a1, float& a2, float& a3, float& a4) {
#pragma unroll
    for (int off = 32; off; off >>= 1) {
      a0 += __shfl_down(a0, off, 64); a1 += __shfl_down(a1, off, 64);
      a2 += __shfl_down(a2, off, 64); a3 += __shfl_down(a3, off, 64);
      a4 += __shfl_down(a4, off, 64);
    }
  };

  // resolve stack-slot h-vector (lane's 4 elements); wave-uniform control
  auto resolveH = [&](int slot, float* x) {
    const int e = ssrc[slot];
    if (e < COMPOSED) {
      const float4 f = *(const float4*)(bufh + (size_t)e * HDIM + 4 * lane);
      x[0] = f.x; x[1] = f.y; x[2] = f.z; x[3] = f.w;
    } else {
      const int ver = e & 0xFFFF;
      if (slot == ccSlot && ver == ccVer) { x[0] = cc0; x[1] = cc1; x[2] = cc2; x[3] = cc3; }
      else gather1T(stkT + (size_t)(ver & 1) * SZ_BUF + (size_t)slot * HDIM, lane,
                    (unsigned)(ver & 3), x);
    }
  };

  auto fin_track = [&]() {   // tid<4 only
    const float gi = g_lds[tid], gf = g_lds[4 + tid], gg = g_lds[8 + tid], go = g_lds[12 + tid];
    const float cn = sigm(gf) * tc_lds[V & 1][tid] + sigm(gi) * tanhf(gg);
    tc_lds[(V + 1) & 1][tid] = cn;
    const float th = sigm(go) * tanhf(cn);
    astore(thP + ((V + 1) & 1) * 1024 + bx * 16 + tid, tagbits(th, V + 1));
    part_lds[tid] = ws0 * th; part_lds[4 + tid] = ws1 * th;
  };
  auto emit_loss = [&]() {   // tid==0, same wave as part_lds writers
    float* lp = lossp + (size_t)V * 128 + bx * 2;
    lp[0] = part_lds[0] + part_lds[1] + part_lds[2] + part_lds[3];
    lp[1] = part_lds[4] + part_lds[5] + part_lds[6] + part_lds[7];
  };

  // ---- initial track: p1 = slot1 (zeros), p2 = slot0 (zeros), p3 = buf[0], th = 0 ----
  {
    const u64* pt = (const u64*)(thP + (V & 1) * 1024) + 8 * lane;   // WG lane's line
    u64 ta = aload64(pt), tb = aload64(pt + 1);
    float p1[4], p2[4];
    resolveH(1, p1); resolveH(0, p2);
    const float4 f3 = *(const float4*)(bufh + 4 * lane);
    const float p3[4] = { f3.x, f3.y, f3.z, f3.w };
    float s0 = 0.f, s1 = 0.f, s2 = 0.f, s3 = 0.f;
#pragma unroll
    for (int c = 0; c < 4; ++c) {
      s0 += wt[0][c] * p1[c] + wt[0][4 + c] * p2[c] + wt[0][8 + c] * p3[c];
      s1 += wt[1][c] * p1[c] + wt[1][4 + c] * p2[c] + wt[1][8 + c] * p3[c];
      s2 += wt[2][c] * p1[c] + wt[2][4 + c] * p2[c] + wt[2][8 + c] * p3[c];
      s3 += wt[3][c] * p1[c] + wt[3][4 + c] * p2[c] + wt[3][8 + c] * p3[c];
    }
    float xth[4];
    spin4(pt, ta, tb, V & 3, xth);
#pragma unroll
    for (int c = 0; c < 4; ++c) {
      s0 += wt[0][12 + c] * xth[c]; s1 += wt[1][12 + c] * xth[c];
      s2 += wt[2][12 + c] * xth[c]; s3 += wt[3][12 + c] * xth[c];
    }
    red4(s0, s1, s2, s3);
    if (lane == 0) {
      g_lds[wv * 4 + 0] = s0 + bt_[0]; g_lds[wv * 4 + 1] = s1 + bt_[1];
      g_lds[wv * 4 + 2] = s2 + bt_[2]; g_lds[wv * 4 + 3] = s3 + bt_[3];
    }
    sync_lds();
    if (tid < 4) fin_track();
    if (tid == 0) emit_loss();
    sync_lds();
    V = 1;
  }

  for (int t = 0; t < nT; ++t) {
    const int tr = (t < 2048) ? trs[t] : transes[t];
    // pre-issue th(V) poll immediately; travels while statics resolve
    const u64* pt = (const u64*)(thP + (V & 1) * 1024) + 8 * lane;   // WG lane's line
    u64 ta = aload64(pt), tb = aload64(pt + 1);
    if (tr) {
      // ==== compose ====
      const int sl1 = sptr - 1, sl2 = sptr - 2;
      const int nvS = vcmp[sl2] + 1;
      float h1[4], h2[4];
      resolveH(sl1, h1);
      resolveH(sl2, h2);
      float a0 = 0.f, a1 = 0.f, a2 = 0.f, a3 = 0.f, a4 = 0.f;
#pragma unroll
      for (int c = 0; c < 4; ++c) {
        a0 += wcm[0][c] * h1[c] + wcm[0][4 + c] * h2[c];
        a1 += wcm[1][c] * h1[c] + wcm[1][4 + c] * h2[c];
        a2 += wcm[2][c] * h1[c] + wcm[2][4 + c] * h2[c];
        a3 += wcm[3][c] * h1[c] + wcm[3][4 + c] * h2[c];
        a4 += wcm[4][c] * h1[c] + wcm[4][4 + c] * h2[c];
      }
      float xth[4];
      spin4(pt, ta, tb, V & 3, xth);
#pragma unroll
      for (int c = 0; c < 4; ++c) {
        a0 += wcm[0][8 + c] * xth[c]; a1 += wcm[1][8 + c] * xth[c];
        a2 += wcm[2][8 + c] * xth[c]; a3 += wcm[3][8 + c] * xth[c];
        a4 += wcm[4][8 + c] * xth[c];
      }
      red5(a0, a1, a2, a3, a4);
      if (lane == 0) {
        g_lds[5 * wv + 0] = a0 + bc_[0]; g_lds[5 * wv + 1] = a1 + bc_[1];
        g_lds[5 * wv + 2] = a2 + bc_[2]; g_lds[5 * wv + 3] = a3 + bc_[3];
        g_lds[5 * wv + 4] = a4 + bc_[4];
      }
      sync_lds();
      const unsigned vrh1 = vrh + 1;
      if (tid < 4) {
        const float ga = g_lds[tid], gi = g_lds[4 + tid], gf1 = g_lds[8 + tid],
                    gf2 = g_lds[12 + tid], go = g_lds[16 + tid];
        const float c1 = sc_lds[sl1][tid];
        const float c2 = sc_lds[sl2][tid];
        const float rc = tanhf(ga) * sigm(gi) + sigm(gf1) * c1 + sigm(gf2) * c2;
        const float rh = sigm(go) * tanhf(rc);
        // critical broadcast first (WG-private padded line, 1 writer):
        astore(rhP + (vrh1 & 1) * 1024 + bx * 16 + tid, tagbits(rh, vrh1));
        sc_lds[sl2][tid] = rc;
        // backing store for generality (off critical path):
        astore(stkT + (size_t)(nvS & 1) * SZ_BUF + (size_t)sl2 * HDIM + j0 + tid,
               tagbits(rh, (unsigned)nvS));
      }
      if (tid == 0) { vcmp[sl2] = nvS; ssrc[sl2] = COMPOSED | nvS; }
      sync_lds();
      vrh = vrh1;

      // ==== trackR: p1 = rh (spin), p2 = slot sptr-3, p3 = buf[bptr], th reused ====
      const u64* pr = (const u64*)(rhP + (vrh & 1) * 1024) + 8 * lane; // WG lane's line
      u64 ra = aload64(pr), rb = aload64(pr + 1);     // pre-issue rh poll
      float p2[4];
      resolveH(sptr - 3, p2);
      const float4 f3 = *(const float4*)(bufh + (size_t)bptr * HDIM + 4 * lane);
      const float x3[4] = { f3.x, f3.y, f3.z, f3.w };
      float s0 = 0.f, s1 = 0.f, s2 = 0.f, s3 = 0.f;
#pragma unroll
      for (int c = 0; c < 4; ++c) {
        s0 += wt[0][4 + c] * p2[c] + wt[0][8 + c] * x3[c] + wt[0][12 + c] * xth[c];
        s1 += wt[1][4 + c] * p2[c] + wt[1][8 + c] * x3[c] + wt[1][12 + c] * xth[c];
        s2 += wt[2][4 + c] * p2[c] + wt[2][8 + c] * x3[c] + wt[2][12 + c] * xth[c];
        s3 += wt[3][4 + c] * p2[c] + wt[3][8 + c] * x3[c] + wt[3][12 + c] * xth[c];
      }
      float rr[4];
      spin4(pr, ra, rb, vrh & 3, rr);
#pragma unroll
      for (int c = 0; c < 4; ++c) {
        s0 += wt[0][c] * rr[c]; s1 += wt[1][c] * rr[c];
        s2 += wt[2][c] * rr[c]; s3 += wt[3][c] * rr[c];
      }
      red4(s0, s1, s2, s3);
      if (lane == 0) {
        g_lds[wv * 4 + 0] = s0 + bt_[0]; g_lds[wv * 4 + 1] = s1 + bt_[1];
        g_lds[wv * 4 + 2] = s2 + bt_[2]; g_lds[wv * 4 + 3] = s3 + bt_[3];
      }
      sync_lds();
      if (tid < 4) fin_track();
      if (tid == 0) emit_loss();
      sync_lds();
      // register-cache the freshly composed vector
      cc0 = rr[0]; cc1 = rr[1]; cc2 = rr[2]; cc3 = rr[3];
      ccSlot = sl2; ccVer = nvS;
      V += 1; sptr -= 1;
    } else {
      // ==== trackS: push = LDS bookkeeping only ====
      const int slot = sptr;
      if (tid < 4) sc_lds[slot][tid] = bufc[(size_t)bptr * HDIM + j0 + tid];
      if (slot == ccSlot) ccSlot = -1;
      float p2[4];
      resolveH(sptr - 1, p2);
      if (tid == 0) ssrc[slot] = bptr;     // consumed next substage (barrier between)
      const float4 f1 = *(const float4*)(bufh + (size_t)bptr * HDIM + 4 * lane);
      const float4 f3 = *(const float4*)(bufh + (size_t)(bptr + 1) * HDIM + 4 * lane);
      const float x1[4] = { f1.x, f1.y, f1.z, f1.w };
      const float x3[4] = { f3.x, f3.y, f3.z, f3.w };
      float s0 = 0.f, s1 = 0.f, s2 = 0.f, s3 = 0.f;
#pragma unroll
      for (int c = 0; c < 4; ++c) {
        s0 += wt[0][c] * x1[c] + wt[0][4 + c] * p2[c] + wt[0][8 + c] * x3[c];
        s1 += wt[1][c] * x1[c] + wt[1][4 + c] * p2[c] + wt[1][8 + c] * x3[c];
        s2 += wt[2][c] * x1[c] + wt[2][4 + c] * p2[c] + wt[2][8 + c] * x3[c];
        s3 += wt[3][c] * x1[c] + wt[3][4 + c] * p2[c] + wt[3][8 + c] * x3[c];
      }
      float xth[4];
      spin4(pt, ta, tb, V & 3, xth);
#pragma unroll
      for (int c = 0; c < 4; ++c) {
        s0 += wt[0][12 + c] * xth[c]; s1 += wt[1][12 + c] * xth[c];
        s2 += wt[2][12 + c] * xth[c]; s3 += wt[3][12 + c] * xth[c];
      }
      red4(s0, s1, s2, s3);
      if (lane == 0) {
        g_lds[wv * 4 + 0] = s0 + bt_[0]; g_lds[wv * 4 + 1] = s1 + bt_[1];
        g_lds[wv * 4 + 2] = s2 + bt_[2]; g_lds[wv * 4 + 3] = s3 + bt_[3];
      }
      sync_lds();
      if (tid < 4) fin_track();
      if (tid == 0) emit_loss();
      sync_lds();
      V += 1; sptr += 1; bptr += 1;
    }
  }
}

// ---------------- loss reduce: 64-WG partial pass + final pass ----------------
__global__ __launch_bounds__(256) void loss1_kernel(const int* __restrict__ transes, int nT,
                                                    const float* __restrict__ bsc,
                                                    const float* __restrict__ ws,
                                                    double* __restrict__ part) {
  const int tid = threadIdx.x;
  const int lane = tid & 63, wv = tid >> 6;
  const float* lossp = ws + O_LOSSP;
  __shared__ double red[4];
  const float b0 = bsc[0], b1 = bsc[1];
  double acc = 0.0;
  const int t0 = blockIdx.x * 32 + wv * 8;
  for (int i = 0; i < 8; ++i) {
    const int t = t0 + i;
    if (t < nT) {
      const float2 p = *(const float2*)(lossp + (size_t)t * 128 + 2 * lane);
      float a0 = p.x, a1 = p.y;
#pragma unroll
      for (int off = 32; off; off >>= 1) {
        a0 += __shfl_down(a0, off, 64);
        a1 += __shfl_down(a1, off, 64);
      }
      if (lane == 0) {
        const float l0 = a0 + b0, l1 = a1 + b1;
        const float mx = fmaxf(l0, l1);
        acc += (double)(mx + logf(expf(l0 - mx) + expf(l1 - mx)) - (transes[t] ? l1 : l0));
      }
    }
  }
  if (lane == 0) red[wv] = acc;
  __syncthreads();
  if (tid == 0) part[blockIdx.x] = red[0] + red[1] + red[2] + red[3];
}

__global__ __launch_bounds__(64) void loss2_kernel(int nT, const double* __restrict__ part,
                                                   float* __restrict__ out) {
  double a = part[threadIdx.x];
#pragma unroll
  for (int off = 32; off; off >>= 1) a += __shfl_down(a, off, 64);
  if (threadIdx.x == 0) out[0] = (float)(a / (double)nT);
}

// ---------------- launch ----------------
extern "C" void kernel_launch(void* const* d_in, const int* in_sizes, int n_in,
                              void* d_out, int out_size, void* d_ws, size_t ws_size,
                              hipStream_t stream) {
  const int*   edu_words = (const int*)d_in[0];
  const int*   edu_poses = (const int*)d_in[1];
  const int*   transes   = (const int*)d_in[2];
  const float* word_emb  = (const float*)d_in[3];
  const float* pos_emb   = (const float*)d_in[4];
  const float* Wu  = (const float*)d_in[5];
  const float* bu  = (const float*)d_in[6];
  const float* Wb  = (const float*)d_in[7];
  const float* bb  = (const float*)d_in[8];
  const float* Wt  = (const float*)d_in[9];
  const float* bt  = (const float*)d_in[10];
  const float* Wp  = (const float*)d_in[11];
  const float* bp  = (const float*)d_in[12];
  const float* Wih = (const float*)d_in[13];
  const float* Whh = (const float*)d_in[14];
  const float* bih = (const float*)d_in[15];
  const float* bhh = (const float*)d_in[16];
  const float* Wc  = (const float*)d_in[17];
  const float* bc  = (const float*)d_in[18];
  const float* Wsc = (const float*)d_in[19];
  const float* bsc = (const float*)d_in[20];
  float* ws  = (float*)d_ws;
  float* out = (float*)d_out;
  int nT = in_sizes[2];

  hipLaunchKernelGGL(prep_kernel, dim3(256), dim3(256), 0, stream, Wu, Wb, Wt, ws);
  hipLaunchKernelGGL(encode_kernel, dim3(NEDU), dim3(256), 0, stream,
                     edu_words, edu_poses, word_emb, pos_emb, bu, bb, bt, ws);
  hipLaunchKernelGGL(proj_kernel, dim3(16, 8), dim3(256), 0, stream, Wp, bp, ws);

  void* args[] = { (void*)&transes, (void*)&nT, (void*)&Wih, (void*)&Whh, (void*)&bih,
                   (void*)&bhh, (void*)&Wc, (void*)&bc, (void*)&Wsc, (void*)&ws };
  hipLaunchCooperativeKernel((const void*)parse_kernel, dim3(NWG), dim3(256), args, 0, stream);

  double* part = (double*)(ws + O_PART);
  hipLaunchKernelGGL(loss1_kernel, dim3(64), dim3(256), 0, stream, transes, nT, bsc,
                     (const float*)ws, part);
  hipLaunchKernelGGL(loss2_kernel, dim3(1), dim3(64), 0, stream, nT,
                     (const double*)part, out);
}